// Round 1
// baseline (1378.569 us; speedup 1.0000x reference)
//
#include <hip/hip_runtime.h>
#include <hip/hip_bf16.h>
#include <cstdint>
#include <cstddef>

#define E_ 8
#define H_ 2048
#define I_ 4096
#define T_ 2048
#define BK 32

typedef __bf16 bf16x8 __attribute__((ext_vector_type(8)));
typedef float f32x4 __attribute__((ext_vector_type(4)));

// round-half-up fp32->bf16, packed pair via v_perm (1 VALU for the pack)
__device__ __forceinline__ unsigned int pack2bf(float a, float b) {
  unsigned int ua = __float_as_uint(a) + 0x8000u;
  unsigned int ub = __float_as_uint(b) + 0x8000u;
  return __builtin_amdgcn_perm(ub, ua, 0x07060302u);  // [bf16(b) : bf16(a)]
}
__device__ __forceinline__ unsigned short f2bf1(float a) {
  return (unsigned short)((__float_as_uint(a) + 0x8000u) >> 16);
}

// async global->LDS, 16B per lane; LDS dest is wave-uniform base + lane*16
__device__ __forceinline__ void gll16(const void* g, void* l) {
  __builtin_amdgcn_global_load_lds(
      (const __attribute__((address_space(1))) void*)g,
      (__attribute__((address_space(3))) void*)l, 16, 0, 0);
}

// ---------------- router: logits, top-1 argmax, sigmoid score, counts ----------------
__global__ void router_kernel(const float* __restrict__ x, const float* __restrict__ rw,
                              float* __restrict__ score, int* __restrict__ eid,
                              int* __restrict__ meta) {
  const int t = blockIdx.x;
  const int lane = threadIdx.x;  // 64 threads = 1 wave
  const float* xr = x + (size_t)t * H_;
  float acc[E_];
#pragma unroll
  for (int e = 0; e < E_; ++e) acc[e] = 0.f;
  for (int k = lane; k < H_; k += 64) {
    float xv = xr[k];
#pragma unroll
    for (int e = 0; e < E_; ++e) acc[e] += xv * rw[e * H_ + k];
  }
#pragma unroll
  for (int e = 0; e < E_; ++e) {
#pragma unroll
    for (int off = 32; off > 0; off >>= 1) acc[e] += __shfl_down(acc[e], off);
  }
  if (lane == 0) {
    int be = 0;
    float bv = acc[0];
#pragma unroll
    for (int e = 1; e < E_; ++e) {
      if (acc[e] > bv) { bv = acc[e]; be = e; }  // strict > keeps first index on ties
    }
    score[t] = 1.f / (1.f + __expf(-bv));
    eid[t] = be;
    atomicAdd(&meta[be], 1);  // counts at meta[0..8)
  }
}

// ---------------- scan: offsets (meta+8, 9 ints) and cursors (meta+20, 8 ints) -------
__global__ void scan_kernel(int* __restrict__ meta) {
  if (threadIdx.x == 0) {
    int s = 0;
    for (int e = 0; e < E_; ++e) {
      meta[8 + e] = s;
      meta[20 + e] = s;
      s += meta[e];
    }
    meta[8 + E_] = s;
  }
}

// ---------------- scatter: xg = bf16(score*x) gathered by expert; xb = bf16(x) -------
__global__ void scatter_kernel(const float* __restrict__ x, const float* __restrict__ score,
                               const int* __restrict__ eid, int* __restrict__ meta,
                               int* __restrict__ gmap, unsigned short* __restrict__ xg,
                               unsigned short* __restrict__ xb) {
  const int t = blockIdx.x;
  __shared__ int gs;
  if (threadIdx.x == 0) {
    int e = eid[t];
    int g = atomicAdd(&meta[20 + e], 1);
    gmap[g] = t;
    gs = g;
  }
  __syncthreads();
  const int g = gs;
  const float s = score[t];
  const float4* xr = (const float4*)(x + (size_t)t * H_);
  uint2* xgr = (uint2*)(xg + (size_t)g * H_);
  uint2* xbr = (uint2*)(xb + (size_t)t * H_);
  for (int i = threadIdx.x; i < H_ / 4; i += 256) {
    float4 v = xr[i];
    uint2 ub, ug;
    ub.x = pack2bf(v.x, v.y);
    ub.y = pack2bf(v.z, v.w);
    ug.x = pack2bf(v.x * s, v.y * s);
    ug.y = pack2bf(v.z * s, v.w * s);
    xbr[i] = ub;
    xgr[i] = ug;
  }
}

// ---------------- gate_up GEMM tile: 128 rows x 64 cols, both gate & up --------------
// A: bf16 [*, H_] row-major (gathered, pre-scaled). Bg/Bu: fp32 [K=H_, ldb] row-major.
// act out: bf16 [*, I_], act[row][col] = silu(gate)*up
__device__ __forceinline__ void gateup_tile(
    const unsigned short* __restrict__ A, int cnt, int mt, int nt,
    const float* __restrict__ Bg, const float* __restrict__ Bu, int ldb,
    unsigned short* __restrict__ actout) {
  __shared__ __align__(16) unsigned short As[128 * BK];  // [row][k]  8 KB
  __shared__ __align__(16) unsigned short Bs[2 * 2048];  // [mat][kb][n(64)][8]  8 KB

  const int tid = threadIdx.x;
  const int wave = tid >> 6, lane = tid & 63;
  const int wm = wave >> 1, wn = wave & 1;
  const int quad = lane >> 4, l16 = lane & 15;

  const unsigned short* ag0 = A + (size_t)(mt * 128 + (tid >> 2)) * H_ + (tid & 3) * 8;
  const unsigned short* ag1 = ag0 + (size_t)64 * H_;
  unsigned short* al0 = As + wave * 512;
  unsigned short* al1 = As + 2048 + wave * 512;

  const int bn = tid & 63;
  const int bkb = tid >> 6;  // 0..3, wave-uniform
  const float* bgp = Bg + (size_t)(bkb * 8) * ldb + nt * 64 + bn;
  const float* bup = Bu + (size_t)(bkb * 8) * ldb + nt * 64 + bn;
  unsigned short* wg = Bs + bkb * 512 + bn * 8;
  unsigned short* wu = Bs + 2048 + bkb * 512 + bn * 8;

  int aoff[4], boff[2];
#pragma unroll
  for (int i = 0; i < 4; ++i) aoff[i] = (wm * 64 + i * 16 + l16) * BK + quad * 8;
#pragma unroll
  for (int i = 0; i < 2; ++i) boff[i] = quad * 512 + (wn * 32 + i * 16 + l16) * 8;

  f32x4 accg[4][2], accu[4][2];
  {
    f32x4 z = {0.f, 0.f, 0.f, 0.f};
#pragma unroll
    for (int m = 0; m < 4; ++m)
#pragma unroll
      for (int n = 0; n < 2; ++n) { accg[m][n] = z; accu[m][n] = z; }
  }

  for (int ko = 0; ko < H_ / BK; ++ko) {
    __syncthreads();
    gll16(ag0, al0);
    gll16(ag1, al1);
    ag0 += BK;
    ag1 += BK;
    float vg[8], vu[8];
#pragma unroll
    for (int j = 0; j < 8; ++j) {
      vg[j] = bgp[(size_t)j * ldb];
      vu[j] = bup[(size_t)j * ldb];
    }
    bgp += (size_t)BK * ldb;
    bup += (size_t)BK * ldb;
    uint4 pg, pu;
    pg.x = pack2bf(vg[0], vg[1]); pg.y = pack2bf(vg[2], vg[3]);
    pg.z = pack2bf(vg[4], vg[5]); pg.w = pack2bf(vg[6], vg[7]);
    pu.x = pack2bf(vu[0], vu[1]); pu.y = pack2bf(vu[2], vu[3]);
    pu.z = pack2bf(vu[4], vu[5]); pu.w = pack2bf(vu[6], vu[7]);
    *(uint4*)wg = pg;
    *(uint4*)wu = pu;
    __syncthreads();

    bf16x8 af[4], bg_[2], bu_[2];
#pragma unroll
    for (int i = 0; i < 4; ++i) af[i] = *(const bf16x8*)(As + aoff[i]);
#pragma unroll
    for (int i = 0; i < 2; ++i) {
      bg_[i] = *(const bf16x8*)(Bs + boff[i]);
      bu_[i] = *(const bf16x8*)(Bs + 2048 + boff[i]);
    }
#pragma unroll
    for (int m = 0; m < 4; ++m)
#pragma unroll
      for (int n = 0; n < 2; ++n) {
        accg[m][n] = __builtin_amdgcn_mfma_f32_16x16x32_bf16(af[m], bg_[n], accg[m][n], 0, 0, 0);
        accu[m][n] = __builtin_amdgcn_mfma_f32_16x16x32_bf16(af[m], bu_[n], accu[m][n], 0, 0, 0);
      }
  }

#pragma unroll
  for (int m = 0; m < 4; ++m) {
    const int rb = mt * 128 + wm * 64 + m * 16 + quad * 4;
#pragma unroll
    for (int n = 0; n < 2; ++n) {
      const int col = nt * 64 + wn * 32 + n * 16 + l16;
#pragma unroll
      for (int r = 0; r < 4; ++r) {
        const int row = rb + r;
        if (row < cnt) {
          float g = accg[m][n][r], u = accu[m][n][r];
          float sig = 1.f / (1.f + __expf(-g));
          actout[(size_t)row * I_ + col] = f2bf1(u * g * sig);
        }
      }
    }
  }
}

// ---------------- down GEMM tile: 128 rows x 128 cols ---------------------------------
__device__ __forceinline__ void down_tile(
    const unsigned short* __restrict__ A, int cnt, int mt, int nt,
    const float* __restrict__ B, float* __restrict__ o, const int* __restrict__ gm) {
  __shared__ __align__(16) unsigned short As[128 * BK];  // [row][k]  8 KB
  __shared__ __align__(16) unsigned short Bs[4096];      // [kb][n(128)][8]  8 KB

  const int tid = threadIdx.x;
  const int wave = tid >> 6, lane = tid & 63;
  const int wm = wave >> 1, wn = wave & 1;
  const int quad = lane >> 4, l16 = lane & 15;

  const unsigned short* ag0 = A + (size_t)(mt * 128 + (tid >> 2)) * I_ + (tid & 3) * 8;
  const unsigned short* ag1 = ag0 + (size_t)64 * I_;
  unsigned short* al0 = As + wave * 512;
  unsigned short* al1 = As + 2048 + wave * 512;

  const int bn = tid & 127;
  const int bkb = tid >> 7;  // 0..1 (+2 for second slot)
  const float* bp0 = B + (size_t)(bkb * 8) * H_ + nt * 128 + bn;
  const float* bp1 = bp0 + (size_t)16 * H_;
  unsigned short* w0 = Bs + bkb * 1024 + bn * 8;
  unsigned short* w1 = w0 + 2048;

  int aoff[4], boff[4];
#pragma unroll
  for (int i = 0; i < 4; ++i) aoff[i] = (wm * 64 + i * 16 + l16) * BK + quad * 8;
#pragma unroll
  for (int i = 0; i < 4; ++i) boff[i] = quad * 1024 + (wn * 64 + i * 16 + l16) * 8;

  f32x4 acc[4][4];
  {
    f32x4 z = {0.f, 0.f, 0.f, 0.f};
#pragma unroll
    for (int m = 0; m < 4; ++m)
#pragma unroll
      for (int n = 0; n < 4; ++n) acc[m][n] = z;
  }

  for (int ko = 0; ko < I_ / BK; ++ko) {
    __syncthreads();
    gll16(ag0, al0);
    gll16(ag1, al1);
    ag0 += BK;
    ag1 += BK;
    float v0[8], v1[8];
#pragma unroll
    for (int j = 0; j < 8; ++j) {
      v0[j] = bp0[(size_t)j * H_];
      v1[j] = bp1[(size_t)j * H_];
    }
    bp0 += (size_t)BK * H_;
    bp1 += (size_t)BK * H_;
    uint4 p0, p1;
    p0.x = pack2bf(v0[0], v0[1]); p0.y = pack2bf(v0[2], v0[3]);
    p0.z = pack2bf(v0[4], v0[5]); p0.w = pack2bf(v0[6], v0[7]);
    p1.x = pack2bf(v1[0], v1[1]); p1.y = pack2bf(v1[2], v1[3]);
    p1.z = pack2bf(v1[4], v1[5]); p1.w = pack2bf(v1[6], v1[7]);
    *(uint4*)w0 = p0;
    *(uint4*)w1 = p1;
    __syncthreads();

    bf16x8 af[4], bf_[4];
#pragma unroll
    for (int i = 0; i < 4; ++i) af[i] = *(const bf16x8*)(As + aoff[i]);
#pragma unroll
    for (int i = 0; i < 4; ++i) bf_[i] = *(const bf16x8*)(Bs + boff[i]);
#pragma unroll
    for (int m = 0; m < 4; ++m)
#pragma unroll
      for (int n = 0; n < 4; ++n)
        acc[m][n] = __builtin_amdgcn_mfma_f32_16x16x32_bf16(af[m], bf_[n], acc[m][n], 0, 0, 0);
  }

#pragma unroll
  for (int m = 0; m < 4; ++m) {
    const int rb = mt * 128 + wm * 64 + m * 16 + quad * 4;
#pragma unroll
    for (int n = 0; n < 4; ++n) {
      const int col = nt * 128 + wn * 64 + n * 16 + l16;
#pragma unroll
      for (int r = 0; r < 4; ++r) {
        const int row = rb + r;
        if (row < cnt) {
          const int trow = gm ? gm[row] : row;
          o[(size_t)trow * H_ + col] = acc[m][n][r];
        }
      }
    }
  }
}

// ---------------- fused wrappers ------------------------------------------------------
__global__ __launch_bounds__(256, 2) void gateup_all_kernel(
    const unsigned short* __restrict__ xg, const unsigned short* __restrict__ xb,
    const float* __restrict__ gup, const float* __restrict__ sgw,
    const float* __restrict__ suw, const int* __restrict__ meta,
    unsigned short* __restrict__ act_r, unsigned short* __restrict__ act_s) {
  const int z = blockIdx.z;
  const unsigned short* A;
  int cnt, ldb;
  const float *Bg, *Bu;
  unsigned short* actout;
  if (z < E_) {
    const int r0 = meta[8 + z];
    cnt = meta[8 + z + 1] - r0;
    A = xg + (size_t)r0 * H_;
    Bg = gup + (size_t)z * H_ * (2 * I_);
    Bu = Bg + I_;
    ldb = 2 * I_;
    actout = act_r + (size_t)r0 * I_;
  } else {
    A = xb;
    cnt = T_;
    Bg = sgw;
    Bu = suw;
    ldb = I_;
    actout = act_s;
  }
  if ((int)blockIdx.y * 128 >= cnt) return;
  gateup_tile(A, cnt, blockIdx.y, blockIdx.x, Bg, Bu, ldb, actout);
}

__global__ __launch_bounds__(256, 2) void down_all_kernel(
    const unsigned short* __restrict__ act_r, const unsigned short* __restrict__ act_s,
    const float* __restrict__ dwn, const float* __restrict__ sdw,
    const int* __restrict__ meta, const int* __restrict__ gmap,
    float* __restrict__ out, float* __restrict__ rbuf) {
  const int z = blockIdx.z;
  const unsigned short* A;
  int cnt;
  const float* B;
  float* o;
  const int* gm;
  if (z < E_) {
    const int r0 = meta[8 + z];
    cnt = meta[8 + z + 1] - r0;
    A = act_r + (size_t)r0 * I_;
    B = dwn + (size_t)z * I_ * H_;
    o = rbuf;
    gm = gmap + r0;
  } else {
    A = act_s;
    cnt = T_;
    B = sdw;
    o = out;
    gm = nullptr;
  }
  if ((int)blockIdx.y * 128 >= cnt) return;
  down_tile(A, cnt, blockIdx.y, blockIdx.x, B, o, gm);
}

__global__ void add_kernel(float* __restrict__ out, const float* __restrict__ rbuf) {
  const int i = blockIdx.x * 256 + threadIdx.x;
  float4 a = ((const float4*)out)[i];
  float4 b = ((const float4*)rbuf)[i];
  a.x += b.x;
  a.y += b.y;
  a.z += b.z;
  a.w += b.w;
  ((float4*)out)[i] = a;
}

extern "C" void kernel_launch(void* const* d_in, const int* in_sizes, int n_in,
                              void* d_out, int out_size, void* d_ws, size_t ws_size,
                              hipStream_t stream) {
  (void)in_sizes; (void)n_in; (void)out_size; (void)ws_size;
  const float* x = (const float*)d_in[0];
  const float* rw = (const float*)d_in[1];
  const float* gup = (const float*)d_in[2];
  const float* dwn = (const float*)d_in[3];
  const float* sgw = (const float*)d_in[4];
  const float* suw = (const float*)d_in[5];
  const float* sdw = (const float*)d_in[6];
  float* out = (float*)d_out;

  // workspace layout (~69 MB): meta | score | eid | gmap | xg | xb | act_r | act_s | rbuf
  char* w = (char*)d_ws;
  int* meta = (int*)w;                       // counts[8] | offs[9] (at +8) | cursor[8] (at +20)
  float* score = (float*)(w + 256);
  int* eid = (int*)(w + 256 + 4 * T_);
  int* gmap = (int*)(w + 256 + 8 * T_);
  size_t off = 256 + 12 * (size_t)T_;
  unsigned short* xg = (unsigned short*)(w + off);
  off += (size_t)(T_ + 128) * H_ * 2;        // +128 rows pad for tile overrun reads
  unsigned short* xb = (unsigned short*)(w + off);
  off += (size_t)T_ * H_ * 2;
  unsigned short* act_r = (unsigned short*)(w + off);
  off += (size_t)(T_ + 128) * I_ * 2;
  unsigned short* act_s = (unsigned short*)(w + off);
  off += (size_t)T_ * I_ * 2;
  float* rbuf = (float*)(w + off);

  hipMemsetAsync(meta, 0, 32, stream);  // zero counts
  router_kernel<<<T_, 64, 0, stream>>>(x, rw, score, eid, meta);
  scan_kernel<<<1, 64, 0, stream>>>(meta);
  scatter_kernel<<<T_, 256, 0, stream>>>(x, score, eid, meta, gmap, xg, xb);
  gateup_all_kernel<<<dim3(I_ / 64, T_ / 128, E_ + 1), 256, 0, stream>>>(
      xg, xb, gup, sgw, suw, meta, act_r, act_s);
  down_all_kernel<<<dim3(H_ / 128, T_ / 128, E_ + 1), 256, 0, stream>>>(
      act_r, act_s, dwn, sdw, meta, gmap, out, rbuf);
  add_kernel<<<(T_ * H_ / 4) / 256, 256, 0, stream>>>(out, rbuf);
}